// Round 9
// baseline (31.938 us; speedup 1.0000x reference)
//
#include <hip/hip_runtime.h>

// BlankEmbedding: out[b,s,:] = sum_{m=0..8} c[m] * emb_table[x[b,s-m], :]
// c[m] from 256-entry constexpr LUT over the 8 preblank bits (verified R2-R8).
// Structure = R7 (best known, 26.9 us): XCD-pinned D-chunking (chunk = bid & 7
// -> 2 MiB table slice per XCD L2), PW=2 positions per wave, one 16-lane token
// window + one ballot per wave, interleaved load->store per position.
// Single change vs R7: PLAIN stores instead of nontemporal (A/B: does L2
// write-aggregation beat NT's early-evict for 1KiB/8KiB-strided writes?).

constexpr int S_LEN = 4096;
constexpr int D_DIM = 2048;
constexpr int NXCD  = 8;
constexpr int CW    = D_DIM / NXCD;   // 256 floats = 1 KiB per chunk
constexpr int PW    = 2;              // positions per wave
constexpr int PB    = 4 * PW;         // 8 positions per block (4 waves)

typedef float f32x4 __attribute__((ext_vector_type(4)));

struct CoefTab { unsigned long long v[256]; };

constexpr CoefTab make_tab() {
    CoefTab t{};
    for (int mask = 0; mask < 256; ++mask) {
        int p[9] = {};
        for (int i = 1; i <= 8; ++i) p[i] = (mask >> (i - 1)) & 1;
        int C[9][9] = {};
        for (int j = 0; j < 9; ++j) C[j][0] = 1;
        for (int k = 1; k <= 8; ++k)
            for (int j = 0; j + k <= 8; ++j)
                for (int m = 8; m >= 1; --m)
                    C[j][m] += p[j + k] * C[j + 1][m - 1];
        unsigned long long pack = 0ULL;
        for (int m = 1; m <= 8; ++m)
            pack |= (unsigned long long)(C[0][m] & 0xff) << ((m - 1) * 8);
        t.v[mask] = pack;
    }
    return t;
}

__device__ __constant__ CoefTab cTab = make_tab();

__global__ __launch_bounds__(256)
void blank_emb_kernel(const int* __restrict__ x,
                      const float* __restrict__ table,
                      float* __restrict__ out) {
    const int bid  = blockIdx.x;
    const int c    = bid & (NXCD - 1);      // D-chunk; round-robin -> XCD-pinned
    const int g    = bid >> 3;              // position group of PB positions
    const int wave = (int)threadIdx.x >> 6;
    const int lane = (int)threadIdx.x & 63;
    const int dcol = c * CW + lane * 4;

    const int pos0 = g * PB + wave * PW;    // wave's first flattened b*S + s
    const int s0   = pos0 & (S_LEN - 1);
    const int* __restrict__ xb = x + (pos0 - s0);

    // ---- one 16-lane token window: t = s0 - 8 + lane, lanes 0..15 ----
    int tv = 2048;                          // sentinel: non-blank
    const int t = s0 - 8 + lane;
    if (lane < 16 && t >= 0 && t < S_LEN) tv = xb[t];
    const unsigned W = (unsigned)__ballot(tv < 16);   // blank bits, lane = t-s0+8

    #pragma unroll
    for (int p = 0; p < PW; ++p) {
        const int s = s0 + p;

        const int tok0 = __builtin_amdgcn_readlane(tv, 8 + p);   // x[s]
        f32x4 a = *(const f32x4*)(table + (size_t)tok0 * D_DIM + dcol);

        // v bit m = blank(x[s-m]), m = 0..8
        const unsigned u  = (W >> p) & 0x1FFu;
        const unsigned v  = __builtin_bitreverse32(u) >> 23;     // reverse9
        const unsigned valid = (s >= 8) ? 0xffu : ((1u << s) - 1u);
        const unsigned mask  =
            __builtin_amdgcn_readfirstlane(v & ~(v >> 1) & valid);
        const unsigned long long pk = cTab.v[mask];              // packed c[1..8]

        if (pk) {                                                // ~6% of positions
            #pragma unroll
            for (int m = 1; m < 9; ++m) {
                const int cf = (int)((pk >> ((m - 1) * 8)) & 0xff);
                if (cf != 0) {
                    const float fc = (float)cf;
                    const int tkm = __builtin_amdgcn_readlane(tv, 8 + p - m);
                    a += fc * *(const f32x4*)(table + (size_t)tkm * D_DIM + dcol);
                }
            }
        }

        *(f32x4*)(out + (size_t)(pos0 + p) * D_DIM + dcol) = a;   // plain store
    }
}

extern "C" void kernel_launch(void* const* d_in, const int* in_sizes, int n_in,
                              void* d_out, int out_size, void* d_ws, size_t ws_size,
                              hipStream_t stream) {
    const int*   x     = (const int*)d_in[0];
    const float* table = (const float*)d_in[1];
    float*       out   = (float*)d_out;

    const int BS = in_sizes[0];                      // B * S = 16384
    const int grid = (BS / PB) * NXCD;               // 16384 blocks
    blank_emb_kernel<<<grid, 256, 0, stream>>>(x, table, out);
}

// Round 10
// 26.631 us; speedup vs baseline: 1.1993x; 1.1993x over previous
//
#include <hip/hip_runtime.h>

// BlankEmbedding: out[b,s,:] = sum_{m=0..8} c[m] * emb_table[x[b,s-m], :]
// c[m] from 256-entry constexpr LUT over the 8 preblank bits (verified R2-R9).
// Structure = R7 (best known, 26.9 us): XCD-pinned D-chunking (chunk = bid & 7
// -> 2 MiB table slice per XCD L2), PW=2 positions per wave, one 16-lane token
// window + one ballot per wave, NONTEMPORAL stores (R9 proved plain stores
// regress: write-allocate evicts the table slice).
// Single change vs R7: 512-thread blocks (8 waves) -> 8192 blocks, halving
// workgroup dispatch count; per-wave work is bit-identical.

constexpr int S_LEN = 4096;
constexpr int D_DIM = 2048;
constexpr int NXCD  = 8;
constexpr int CW    = D_DIM / NXCD;   // 256 floats = 1 KiB per chunk
constexpr int PW    = 2;              // positions per wave
constexpr int WPB   = 8;              // waves per block (512 threads)
constexpr int PB    = WPB * PW;       // 16 positions per block

typedef float f32x4 __attribute__((ext_vector_type(4)));

struct CoefTab { unsigned long long v[256]; };

constexpr CoefTab make_tab() {
    CoefTab t{};
    for (int mask = 0; mask < 256; ++mask) {
        int p[9] = {};
        for (int i = 1; i <= 8; ++i) p[i] = (mask >> (i - 1)) & 1;
        int C[9][9] = {};
        for (int j = 0; j < 9; ++j) C[j][0] = 1;
        for (int k = 1; k <= 8; ++k)
            for (int j = 0; j + k <= 8; ++j)
                for (int m = 8; m >= 1; --m)
                    C[j][m] += p[j + k] * C[j + 1][m - 1];
        unsigned long long pack = 0ULL;
        for (int m = 1; m <= 8; ++m)
            pack |= (unsigned long long)(C[0][m] & 0xff) << ((m - 1) * 8);
        t.v[mask] = pack;
    }
    return t;
}

__device__ __constant__ CoefTab cTab = make_tab();

__global__ __launch_bounds__(512)
void blank_emb_kernel(const int* __restrict__ x,
                      const float* __restrict__ table,
                      float* __restrict__ out) {
    const int bid  = blockIdx.x;
    const int c    = bid & (NXCD - 1);      // D-chunk; round-robin -> XCD-pinned
    const int g    = bid >> 3;              // position group of PB positions
    const int wave = (int)threadIdx.x >> 6;
    const int lane = (int)threadIdx.x & 63;
    const int dcol = c * CW + lane * 4;

    const int pos0 = g * PB + wave * PW;    // wave's first flattened b*S + s
    const int s0   = pos0 & (S_LEN - 1);
    const int* __restrict__ xb = x + (pos0 - s0);

    // ---- one 16-lane token window: t = s0 - 8 + lane, lanes 0..15 ----
    int tv = 2048;                          // sentinel: non-blank
    const int t = s0 - 8 + lane;
    if (lane < 16 && t >= 0 && t < S_LEN) tv = xb[t];
    const unsigned W = (unsigned)__ballot(tv < 16);   // blank bits, lane = t-s0+8

    #pragma unroll
    for (int p = 0; p < PW; ++p) {
        const int s = s0 + p;

        const int tok0 = __builtin_amdgcn_readlane(tv, 8 + p);   // x[s]
        f32x4 a = *(const f32x4*)(table + (size_t)tok0 * D_DIM + dcol);

        // v bit m = blank(x[s-m]), m = 0..8
        const unsigned u  = (W >> p) & 0x1FFu;
        const unsigned v  = __builtin_bitreverse32(u) >> 23;     // reverse9
        const unsigned valid = (s >= 8) ? 0xffu : ((1u << s) - 1u);
        const unsigned mask  =
            __builtin_amdgcn_readfirstlane(v & ~(v >> 1) & valid);
        const unsigned long long pk = cTab.v[mask];              // packed c[1..8]

        if (pk) {                                                // ~6% of positions
            #pragma unroll
            for (int m = 1; m < 9; ++m) {
                const int cf = (int)((pk >> ((m - 1) * 8)) & 0xff);
                if (cf != 0) {
                    const float fc = (float)cf;
                    const int tkm = __builtin_amdgcn_readlane(tv, 8 + p - m);
                    a += fc * *(const f32x4*)(table + (size_t)tkm * D_DIM + dcol);
                }
            }
        }

        __builtin_nontemporal_store(
            a, (f32x4*)(out + (size_t)(pos0 + p) * D_DIM + dcol));
    }
}

extern "C" void kernel_launch(void* const* d_in, const int* in_sizes, int n_in,
                              void* d_out, int out_size, void* d_ws, size_t ws_size,
                              hipStream_t stream) {
    const int*   x     = (const int*)d_in[0];
    const float* table = (const float*)d_in[1];
    float*       out   = (float*)d_out;

    const int BS = in_sizes[0];                      // B * S = 16384
    const int grid = (BS / PB) * NXCD;               // 8192 blocks
    blank_emb_kernel<<<grid, 512, 0, stream>>>(x, table, out);
}